// Round 6
// baseline (363.571 us; speedup 1.0000x reference)
//
#include <hip/hip_runtime.h>
#include <hip/hip_bf16.h>
#include <math.h>

// Problem constants
#define BB 256
#define TT 512
#define EE 128
#define HH 128
#define NC 4

typedef float f32x4 __attribute__((ext_vector_type(4)));

// Branch-free tanh: 1 - 2/(1+e^{2x}) with e^{2x} = exp2(2*log2e*x).
__device__ __forceinline__ float fast_tanh(float x) {
    float t = __builtin_amdgcn_exp2f(x * 2.885390081777927f);
    return 1.f - 2.f * __builtin_amdgcn_rcpf(1.f + t);
}

// Workgroup barrier that does NOT drain vmcnt (unlike __syncthreads, which
// emits s_waitcnt vmcnt(0) lgkmcnt(0) before s_barrier). LDS ordering needs
// only lgkmcnt(0); global prefetch loads stay in flight across steps.
__device__ __forceinline__ void lds_barrier() {
    asm volatile("s_waitcnt lgkmcnt(0)" ::: "memory");
    __builtin_amdgcn_s_barrier();
    asm volatile("" ::: "memory");
}

// Cross-lane sum with the xor-16 / xor-32 partner via gfx950's
// v_permlane{16,32}_swap (VALU pipe, ~4cy) instead of ds_bpermute
// (DS pipe, ~120cy latency). With both inputs = p, the two outputs are
// {p[self], p[partner]} in some order on every lane, so t1+t2 is the
// pair-sum regardless of the swap's row-direction convention.
__device__ __forceinline__ float xor16_sum(float p) {
    float t1 = p, t2 = p;
    asm volatile("v_permlane16_swap_b32 %0, %1" : "+v"(t1), "+v"(t2));
    return t1 + t2;
}
__device__ __forceinline__ float xor32_sum(float p) {
    float t1 = p, t2 = p;
    asm volatile("v_permlane32_swap_b32 %0, %1" : "+v"(t1), "+v"(t2));
    return t1 + t2;
}

// ---------------------------------------------------------------------------
// FUSED scan:  h_t = tanh( W_ih·emb[x[t]] + b + W_hh·h_{t-1} )   (512 steps)
//
// Round 10. Round-9 post-mortem: step = 816cy with DS issue ~430 + VALU ~290
// (VALUBusy 36%); scan is jointly issue/latency bound at 1 wave/SIMD and four
// structural variants all land 795-850cy -> little left here. The bigger
// cost was embed_gemm (~85us) + 128MB x_proj HBM round trip. W_ih·e(t) does
// NOT depend on h -> it's off the critical path: compute it IN the scan's
// idle VALU slots and delete the GEMM kernel + workspace traffic entirely.
//
// Structure (unchanged from round-9 core):
//  - 4 waves; lane (kq=l>>4, oo=l&15) owns outputs A=32w+oo, Bo=A+16 over
//    K-quarter [32kq,32kq+32). 8 conflict-free ds_read_b128 (chunk-rotation
//    swizzle folded into weight load order). permlane16+32 K-reduce (VALU).
//  - Double-buffered h_s, one raw s_barrier per step (no vmcnt drain).
// Added:
//  - Resident W_ih slice (same mapping, 64 VGPRs, pinned).
//  - Index ring xi[8] (wave-uniform -> scalar loads, 8 steps ahead).
//  - EB[8] f32x4: emb row e(t+2) in flight; consumed at t into partial
//    scalars xpp[2] for step t+1; ~1700cy load slack vs ~500cy L3 latency.
//  - One permlane reduce serves W_hh·h + W_ih·e (sum of partials); bias
//    (b_ih+b_hh, preloaded) added once post-reduce. W_ih·e is exact f32
//    (better than the old 3-term bf16 split).
// ---------------------------------------------------------------------------
__global__ __launch_bounds__(256, 1) void rnn_scan_fused(
    const int* __restrict__ x, const float* __restrict__ emb,
    const float* __restrict__ Wih, const float* __restrict__ Whh,
    const float* __restrict__ bih, const float* __restrict__ bhh,
    const float* __restrict__ h0, float* __restrict__ hlast)
{
    const int b    = blockIdx.x;
    const int tid  = threadIdx.x;
    const int w    = tid >> 6;       // wave id: owns outputs [32w, 32w+32)
    const int lane = tid & 63;
    const int oo   = lane & 15;      // output column within wave's slice
    const int kq   = lane >> 4;      // K-quarter: [32kq, 32kq+32)

    const int A  = w * 32 + oo;      // first output row
    const int Bo = A + 16;           // second output row

    __shared__ float h_s[2][128];    // double buffer, SWIZZLED layout

    // W_hh: physical chunk order uu=(u+kq)&7 so the 4 kq groups' per-step
    // LDS reads hit disjoint bank groups (swizzle folded into load order).
    f32x4 wA[8], wB[8];
#pragma unroll
    for (int uu = 0; uu < 8; ++uu) {
        int ul = (uu + 8 - kq) & 7;   // logical chunk stored at uu
        wA[uu] = *(const f32x4*)(Whh + (size_t)A  * 128 + kq * 32 + ul * 4);
        wB[uu] = *(const f32x4*)(Whh + (size_t)Bo * 128 + kq * 32 + ul * 4);
    }
    // W_ih: plain chunk order (consumed against EB which is loaded plain).
    f32x4 iA[8], iB[8];
#pragma unroll
    for (int u = 0; u < 8; ++u) {
        iA[u] = *(const f32x4*)(Wih + (size_t)A  * 128 + kq * 32 + u * 4);
        iB[u] = *(const f32x4*)(Wih + (size_t)Bo * 128 + kq * 32 + u * 4);
    }
    // Pin: asm results cannot be rematerialized -> all weights stay in VGPRs.
#pragma unroll
    for (int c = 0; c < 8; ++c) {
        asm volatile("" : "+v"(wA[c]), "+v"(wB[c]));
        asm volatile("" : "+v"(iA[c]), "+v"(iB[c]));
    }

    const float bsA = bih[A]  + bhh[A];
    const float bsB = bih[Bo] + bhh[Bo];

    // Stage h0 (swizzled).
    if (tid < 128) {
        int q = tid >> 5, u = (tid >> 2) & 7, e = tid & 3;
        h_s[0][q * 32 + ((u + q) & 7) * 4 + e] = h0[b * 128 + tid];
    }

    // Writer-side swizzled indices (computed once).
    const int wrA = w * 32 + (((oo >> 2) + w) & 7) * 4 + (oo & 3);
    const int wrB = w * 32 + ((4 + (oo >> 2) + w) & 7) * 4 + (oo & 3);

    // Index ring (wave-uniform values -> scalar loads), 8 steps ahead.
    const int* xb = x + b * TT;
    int xi[8];
#pragma unroll
    for (int s = 0; s < 8; ++s) xi[s] = xb[s];

    // Prologue: xpp for step 0 from e(0); then e(1) in flight in EB.
    f32x4 EB[8];
    float xppA[2], xppB[2];
    {
        const float* er = emb + (size_t)xi[0] * 128 + kq * 32;
#pragma unroll
        for (int u = 0; u < 8; ++u) EB[u] = *(const f32x4*)(er + u * 4);
        f32x4 sA = f32x4{0.f, 0.f, 0.f, 0.f};
        f32x4 sB = f32x4{0.f, 0.f, 0.f, 0.f};
#pragma unroll
        for (int u = 0; u < 8; ++u) { sA += iA[u] * EB[u]; sB += iB[u] * EB[u]; }
        xppA[0] = (sA[0] + sA[1]) + (sA[2] + sA[3]);
        xppB[0] = (sB[0] + sB[1]) + (sB[2] + sB[3]);
        er = emb + (size_t)xi[1] * 128 + kq * 32;
#pragma unroll
        for (int u = 0; u < 8; ++u) EB[u] = *(const f32x4*)(er + u * 4);
    }
    lds_barrier();

    for (int tw = 0; tw < TT; tw += 8) {
#pragma unroll
        for (int ts = 0; ts < 8; ++ts) {
            const int c = ts & 1;    // static double-buffer index
            // --- critical path: 8 conflict-free b128 reads of h K-quarter
            const float* hq = &h_s[c][kq * 32];
            f32x4 h4[8];
#pragma unroll
            for (int uu = 0; uu < 8; ++uu) h4[uu] = *(const f32x4*)&hq[uu * 4];

            f32x4 sA = f32x4{0.f, 0.f, 0.f, 0.f};
            f32x4 sB = f32x4{0.f, 0.f, 0.f, 0.f};
#pragma unroll
            for (int uu = 0; uu < 8; ++uu) {
                sA += wA[uu] * h4[uu];
                sB += wB[uu] * h4[uu];
            }
            float pA = (sA[0] + sA[1]) + (sA[2] + sA[3]) + xppA[c];
            float pB = (sB[0] + sB[1]) + (sB[2] + sB[3]) + xppB[c];

            // --- off-path: consume EB (= e(t+1)) into xpp for next step,
            // then refill EB with e(t+2). Fills VALU bubbles; not on the
            // h-dependent chain. (At the final step the result is unused.)
            {
                f32x4 cA = f32x4{0.f, 0.f, 0.f, 0.f};
                f32x4 cB = f32x4{0.f, 0.f, 0.f, 0.f};
#pragma unroll
                for (int u = 0; u < 8; ++u) { cA += iA[u] * EB[u]; cB += iB[u] * EB[u]; }
                xppA[c ^ 1] = (cA[0] + cA[1]) + (cA[2] + cA[3]);
                xppB[c ^ 1] = (cB[0] + cB[1]) + (cB[2] + cB[3]);
                const float* er = emb + (size_t)xi[(ts + 2) & 7] * 128 + kq * 32;
#pragma unroll
                for (int u = 0; u < 8; ++u) EB[u] = *(const f32x4*)(er + u * 4);
            }

            // --- reduce over the 4 K-quarters entirely on the VALU pipe.
            pA = xor16_sum(pA);  pB = xor16_sum(pB);
            pA = xor32_sum(pA);  pB = xor32_sum(pB);

            float hA = fast_tanh(pA + bsA);
            float hB = fast_tanh(pB + bsB);
            if (kq == 0) {
                h_s[c ^ 1][wrA] = hA;
                h_s[c ^ 1][wrB] = hB;
            }
            // refill index ring slot (stale values stay valid addresses)
            if (tw + 8 < TT) xi[ts] = xb[tw + 8 + ts];
            lds_barrier();
        }
    }
    if (tid < 128) {
        int q = tid >> 5, u = (tid >> 2) & 7, e = tid & 3;
        hlast[b * 128 + tid] = h_s[0][q * 32 + ((u + q) & 7) * 4 + e];
    }
}

// ---------------------------------------------------------------------------
// Kernel 3: MLP head. hidden = relu(h @ W1^T + b1) [256]; logits = hidden @ W2^T + b2 [4]
// One block per batch row. Also writes last_hidden to d_out. (unchanged)
// ---------------------------------------------------------------------------
__global__ __launch_bounds__(256, 2) void mlp_head(
    const float* __restrict__ hlast, const float* __restrict__ W1,
    const float* __restrict__ b1, const float* __restrict__ W2,
    const float* __restrict__ b2, float* __restrict__ out)
{
    const int b = blockIdx.x, tid = threadIdx.x;
    __shared__ float h_row[128];
    __shared__ float hid[256];

    if (tid < 128) {
        float hv = hlast[b * 128 + tid];
        h_row[tid] = hv;
        out[1024 + b * 128 + tid] = hv;   // last_hidden output (fp32)
    }
    __syncthreads();

    // hidden[tid] = relu(b1[tid] + sum_k W1[tid][k] * h[k]); W1 from L2
    {
        float acc = b1[tid];
        const float4* wrow = (const float4*)(W1 + (size_t)tid * 128);
#pragma unroll
        for (int k4 = 0; k4 < 32; ++k4) {
            float4 wv = wrow[k4];
            acc += wv.x * h_row[k4 * 4 + 0] + wv.y * h_row[k4 * 4 + 1]
                 + wv.z * h_row[k4 * 4 + 2] + wv.w * h_row[k4 * 4 + 3];
        }
        hid[tid] = fmaxf(acc, 0.f);
    }
    __syncthreads();

    // logits: wave w -> class w; 64-lane strided partials + shuffle reduce
    const int wv = tid >> 6, lane = tid & 63;
    float s = 0.f;
#pragma unroll
    for (int qq = 0; qq < 4; ++qq)
        s += hid[qq * 64 + lane] * W2[wv * 256 + qq * 64 + lane];
#pragma unroll
    for (int off = 32; off > 0; off >>= 1) s += __shfl_down(s, off);
    if (lane == 0) out[b * 4 + wv] = s + b2[wv];
}

// ---------------------------------------------------------------------------
extern "C" void kernel_launch(void* const* d_in, const int* in_sizes, int n_in,
                              void* d_out, int out_size, void* d_ws, size_t ws_size,
                              hipStream_t stream)
{
    const int*   x   = (const int*)d_in[0];
    const float* h0  = (const float*)d_in[1];
    const float* emb = (const float*)d_in[2];
    const float* Wih = (const float*)d_in[3];
    const float* Whh = (const float*)d_in[4];
    const float* bih = (const float*)d_in[5];
    const float* bhh = (const float*)d_in[6];
    const float* W1  = (const float*)d_in[7];
    const float* b1  = (const float*)d_in[8];
    const float* W2  = (const float*)d_in[9];
    const float* b2  = (const float*)d_in[10];
    float* out = (float*)d_out;

    // Workspace: only the last-hidden buffer (128 KB) is needed now.
    float* hl = (float*)d_ws;

    rnn_scan_fused<<<BB, 256, 0, stream>>>(x, emb, Wih, Whh, bih, bhh, h0, hl);
    mlp_head<<<BB, 256, 0, stream>>>(hl, W1, b1, W2, b2, out);
}

// Round 8
// 349.580 us; speedup vs baseline: 1.0400x; 1.0400x over previous
//
#include <hip/hip_runtime.h>
#include <hip/hip_bf16.h>
#include <math.h>

// Problem constants
#define BB 256
#define TT 512
#define EE 128
#define HH 128
#define NC 4

typedef float f32x4 __attribute__((ext_vector_type(4)));

// Branch-free tanh: 1 - 2/(1+e^{2x}) with e^{2x} = exp2(2*log2e*x).
__device__ __forceinline__ float fast_tanh(float x) {
    float t = __builtin_amdgcn_exp2f(x * 2.885390081777927f);
    return 1.f - 2.f * __builtin_amdgcn_rcpf(1.f + t);
}

// Workgroup barrier that does NOT drain vmcnt (unlike __syncthreads, which
// emits s_waitcnt vmcnt(0) lgkmcnt(0) before s_barrier). LDS ordering needs
// only lgkmcnt(0); global prefetch loads stay in flight across steps.
__device__ __forceinline__ void lds_barrier() {
    asm volatile("s_waitcnt lgkmcnt(0)" ::: "memory");
    __builtin_amdgcn_s_barrier();
    asm volatile("" ::: "memory");
}

// Cross-lane sum with the xor-16 / xor-32 partner via gfx950's
// v_permlane{16,32}_swap (VALU pipe, ~4cy) instead of ds_bpermute
// (DS pipe, ~120cy latency). With both inputs = p, the two outputs are
// {p[self], p[partner]} in some order on every lane, so t1+t2 is the
// pair-sum regardless of the swap's row-direction convention.
__device__ __forceinline__ float xor16_sum(float p) {
    float t1 = p, t2 = p;
    asm volatile("v_permlane16_swap_b32 %0, %1" : "+v"(t1), "+v"(t2));
    return t1 + t2;
}
__device__ __forceinline__ float xor32_sum(float p) {
    float t1 = p, t2 = p;
    asm volatile("v_permlane32_swap_b32 %0, %1" : "+v"(t1), "+v"(t2));
    return t1 + t2;
}

// ---------------------------------------------------------------------------
// FUSED scan:  h_t = tanh( W_ih·emb[x[t]] + b + W_hh·h_{t-1} )   (512 steps)
//
// Round 12 = the PASSING round-10 kernel + two verified-minimal fixes.
// Round-11 (failed) is reverted wholesale.
//
// Round-10 re-diagnosis from counters:
//  (a) VGPR_Count=120 but wA/wB+iA/iB alone = 256 regs -> weights were NOT
//      resident; allocator spilled/refetched (scratch is L2-backed ->
//      invisible in FETCH_SIZE). Fix attempt: amdgpu_waves_per_eu(1) to
//      open the 512-reg budget (1 block/CU anyway; nothing to lose).
//  (b) per-step index refill was a wave-uniform s_load (lgkmcnt) issued
//      right before lds_barrier's lgkmcnt(0) -> ~200-300cy drained on the
//      critical path EVERY step. Fix: cur[8]/nxt[8]; nxt batch-loaded
//      (clamped) at group start (drained once per 8 steps, with ~1 step of
//      slack); cur<-nxt register copy at group end; all indices into the
//      arrays are compile-time after unroll.
//  (c) instruction order: issue the 8 ds_read_b128, then the INDEPENDENT
//      emb-consume FMAs (~130cy) to cover ds_read latency, then EB refill
//      loads (vmcnt, not drained by lds_barrier), then W_hh FMAs. Pure
//      reorder; identical FP results.
// EB stays depth-1 (round-10 proven scheme): EB holds e(t+1) at step t,
// consumed into xpp[c^1] for step t+1, refilled with e(t+2) via cur/nxt.
// Core scan structure unchanged (round-9 best measured):
//  - 4 waves; lane (kq=l>>4, oo=l&15) owns outputs A=32w+oo, Bo=A+16 over
//    K-quarter [32kq,32kq+32). 8 conflict-free ds_read_b128 (chunk-rotation
//    swizzle folded into weight load order). permlane16+32 K-reduce (VALU).
//  - Double-buffered h_s, one raw s_barrier per step.
// ---------------------------------------------------------------------------
__global__ __launch_bounds__(256, 1)
__attribute__((amdgpu_waves_per_eu(1)))
void rnn_scan_fused(
    const int* __restrict__ x, const float* __restrict__ emb,
    const float* __restrict__ Wih, const float* __restrict__ Whh,
    const float* __restrict__ bih, const float* __restrict__ bhh,
    const float* __restrict__ h0, float* __restrict__ hlast)
{
    const int b    = blockIdx.x;
    const int tid  = threadIdx.x;
    const int w    = tid >> 6;       // wave id: owns outputs [32w, 32w+32)
    const int lane = tid & 63;
    const int oo   = lane & 15;      // output column within wave's slice
    const int kq   = lane >> 4;      // K-quarter: [32kq, 32kq+32)

    const int A  = w * 32 + oo;      // first output row
    const int Bo = A + 16;           // second output row

    __shared__ float h_s[2][128];    // double buffer, SWIZZLED layout

    // W_hh: physical chunk order uu=(u+kq)&7 so the 4 kq groups' per-step
    // LDS reads hit disjoint bank groups (swizzle folded into load order).
    f32x4 wA[8], wB[8];
#pragma unroll
    for (int uu = 0; uu < 8; ++uu) {
        int ul = (uu + 8 - kq) & 7;   // logical chunk stored at uu
        wA[uu] = *(const f32x4*)(Whh + (size_t)A  * 128 + kq * 32 + ul * 4);
        wB[uu] = *(const f32x4*)(Whh + (size_t)Bo * 128 + kq * 32 + ul * 4);
    }
    // W_ih: plain chunk order (consumed against EB which is loaded plain).
    f32x4 iA[8], iB[8];
#pragma unroll
    for (int u = 0; u < 8; ++u) {
        iA[u] = *(const f32x4*)(Wih + (size_t)A  * 128 + kq * 32 + u * 4);
        iB[u] = *(const f32x4*)(Wih + (size_t)Bo * 128 + kq * 32 + u * 4);
    }
    // Pin: asm results cannot be rematerialized -> weights stay resident.
#pragma unroll
    for (int c = 0; c < 8; ++c) {
        asm volatile("" : "+v"(wA[c]), "+v"(wB[c]));
        asm volatile("" : "+v"(iA[c]), "+v"(iB[c]));
    }

    const float bsA = bih[A]  + bhh[A];
    const float bsB = bih[Bo] + bhh[Bo];

    // Stage h0 (swizzled).
    if (tid < 128) {
        int q = tid >> 5, u = (tid >> 2) & 7, e = tid & 3;
        h_s[0][q * 32 + ((u + q) & 7) * 4 + e] = h0[b * 128 + tid];
    }

    // Writer-side swizzled indices (computed once).
    const int wrA = w * 32 + (((oo >> 2) + w) & 7) * 4 + (oo & 3);
    const int wrB = w * 32 + ((4 + (oo >> 2) + w) & 7) * 4 + (oo & 3);

    // Token-index arrays: cur = this group's 8 indices, nxt = next group's.
    const int* xb = x + b * TT;
    int cur[8], nxt[8];
#pragma unroll
    for (int s = 0; s < 8; ++s) cur[s] = xb[s];

    // Prologue (round-10 exact): xpp for step 0 from e(0); EB <- e(1).
    f32x4 EB[8];
    float xppA[2], xppB[2];
    {
        const float* er = emb + (size_t)cur[0] * 128 + kq * 32;
#pragma unroll
        for (int u = 0; u < 8; ++u) EB[u] = *(const f32x4*)(er + u * 4);
        f32x4 sA = f32x4{0.f, 0.f, 0.f, 0.f};
        f32x4 sB = f32x4{0.f, 0.f, 0.f, 0.f};
#pragma unroll
        for (int u = 0; u < 8; ++u) { sA += iA[u] * EB[u]; sB += iB[u] * EB[u]; }
        xppA[0] = (sA[0] + sA[1]) + (sA[2] + sA[3]);
        xppB[0] = (sB[0] + sB[1]) + (sB[2] + sB[3]);
        er = emb + (size_t)cur[1] * 128 + kq * 32;
#pragma unroll
        for (int u = 0; u < 8; ++u) EB[u] = *(const f32x4*)(er + u * 4);
    }
    lds_barrier();

    for (int tw = 0; tw < TT; tw += 8) {
        // Batch-load next group's indices (wave-uniform s_loads, issued
        // right after the previous barrier; first drained at the end of
        // step 0 with ~1 full step of slack; amortized /8).
#pragma unroll
        for (int s = 0; s < 8; ++s) {
            int src = tw + 8 + s;
            nxt[s] = xb[src < TT ? src : TT - 1];
        }
#pragma unroll
        for (int ts = 0; ts < 8; ++ts) {
            const int c = ts & 1;    // static double-buffer index
            // (1) issue the 8 conflict-free b128 reads of h K-quarter
            const float* hq = &h_s[c][kq * 32];
            f32x4 h4[8];
#pragma unroll
            for (int uu = 0; uu < 8; ++uu) h4[uu] = *(const f32x4*)&hq[uu * 4];

            // (2) independent work under ds_read latency: consume EB
            // (= e(t+1), loaded at t-1) -> xpp for step t+1.
            {
                f32x4 cA = f32x4{0.f, 0.f, 0.f, 0.f};
                f32x4 cB = f32x4{0.f, 0.f, 0.f, 0.f};
#pragma unroll
                for (int u = 0; u < 8; ++u) { cA += iA[u] * EB[u]; cB += iB[u] * EB[u]; }
                xppA[c ^ 1] = (cA[0] + cA[1]) + (cA[2] + cA[3]);
                xppB[c ^ 1] = (cB[0] + cB[1]) + (cB[2] + cB[3]);
            }
            // (3) refill EB with e(t+2); vector loads stay in flight across
            // the raw barrier (no vmcnt drain). Index x(t+2): ts<6 from cur,
            // ts>=6 from nxt -- compile-time selection after unroll.
            {
                int ei = (ts < 6) ? cur[(ts + 2) & 7] : nxt[(ts + 2) & 7];
                const float* er = emb + (size_t)ei * 128 + kq * 32;
#pragma unroll
                for (int u = 0; u < 8; ++u) EB[u] = *(const f32x4*)(er + u * 4);
            }

            // (4) critical path: W_hh FMAs on h4 (ds latency now covered)
            f32x4 sA = f32x4{0.f, 0.f, 0.f, 0.f};
            f32x4 sB = f32x4{0.f, 0.f, 0.f, 0.f};
#pragma unroll
            for (int uu = 0; uu < 8; ++uu) {
                sA += wA[uu] * h4[uu];
                sB += wB[uu] * h4[uu];
            }
            float pA = (sA[0] + sA[1]) + (sA[2] + sA[3]) + xppA[c];
            float pB = (sB[0] + sB[1]) + (sB[2] + sB[3]) + xppB[c];
            // Reduce over the 4 K-quarters entirely on the VALU pipe.
            pA = xor16_sum(pA);  pB = xor16_sum(pB);
            pA = xor32_sum(pA);  pB = xor32_sum(pB);

            float hA = fast_tanh(pA + bsA);
            float hB = fast_tanh(pB + bsB);
            if (kq == 0) {
                h_s[c ^ 1][wrA] = hA;
                h_s[c ^ 1][wrB] = hB;
            }
            lds_barrier();
        }
        // Rotate index arrays (register copies).
#pragma unroll
        for (int s = 0; s < 8; ++s) cur[s] = nxt[s];
    }

    if (tid < 128) {
        int q = tid >> 5, u = (tid >> 2) & 7, e = tid & 3;
        hlast[b * 128 + tid] = h_s[0][q * 32 + ((u + q) & 7) * 4 + e];
    }
}

// ---------------------------------------------------------------------------
// Kernel 3: MLP head. hidden = relu(h @ W1^T + b1) [256]; logits = hidden @ W2^T + b2 [4]
// One block per batch row. Also writes last_hidden to d_out. (unchanged)
// ---------------------------------------------------------------------------
__global__ __launch_bounds__(256, 2) void mlp_head(
    const float* __restrict__ hlast, const float* __restrict__ W1,
    const float* __restrict__ b1, const float* __restrict__ W2,
    const float* __restrict__ b2, float* __restrict__ out)
{
    const int b = blockIdx.x, tid = threadIdx.x;
    __shared__ float h_row[128];
    __shared__ float hid[256];

    if (tid < 128) {
        float hv = hlast[b * 128 + tid];
        h_row[tid] = hv;
        out[1024 + b * 128 + tid] = hv;   // last_hidden output (fp32)
    }
    __syncthreads();

    // hidden[tid] = relu(b1[tid] + sum_k W1[tid][k] * h[k]); W1 from L2
    {
        float acc = b1[tid];
        const float4* wrow = (const float4*)(W1 + (size_t)tid * 128);
#pragma unroll
        for (int k4 = 0; k4 < 32; ++k4) {
            float4 wv = wrow[k4];
            acc += wv.x * h_row[k4 * 4 + 0] + wv.y * h_row[k4 * 4 + 1]
                 + wv.z * h_row[k4 * 4 + 2] + wv.w * h_row[k4 * 4 + 3];
        }
        hid[tid] = fmaxf(acc, 0.f);
    }
    __syncthreads();

    // logits: wave w -> class w; 64-lane strided partials + shuffle reduce
    const int wv = tid >> 6, lane = tid & 63;
    float s = 0.f;
#pragma unroll
    for (int qq = 0; qq < 4; ++qq)
        s += hid[qq * 64 + lane] * W2[wv * 256 + qq * 64 + lane];
#pragma unroll
    for (int off = 32; off > 0; off >>= 1) s += __shfl_down(s, off);
    if (lane == 0) out[b * 4 + wv] = s + b2[wv];
}

// ---------------------------------------------------------------------------
extern "C" void kernel_launch(void* const* d_in, const int* in_sizes, int n_in,
                              void* d_out, int out_size, void* d_ws, size_t ws_size,
                              hipStream_t stream)
{
    const int*   x   = (const int*)d_in[0];
    const float* h0  = (const float*)d_in[1];
    const float* emb = (const float*)d_in[2];
    const float* Wih = (const float*)d_in[3];
    const float* Whh = (const float*)d_in[4];
    const float* bih = (const float*)d_in[5];
    const float* bhh = (const float*)d_in[6];
    const float* W1  = (const float*)d_in[7];
    const float* b1  = (const float*)d_in[8];
    const float* W2  = (const float*)d_in[9];
    const float* b2  = (const float*)d_in[10];
    float* out = (float*)d_out;

    // Workspace: only the last-hidden buffer (128 KB) is needed now.
    float* hl = (float*)d_ws;

    rnn_scan_fused<<<BB, 256, 0, stream>>>(x, emb, Wih, Whh, bih, bhh, h0, hl);
    mlp_head<<<BB, 256, 0, stream>>>(hl, W1, b1, W2, b2, out);
}